// Round 24
// baseline (217.437 us; speedup 1.0000x reference)
//
#include <hip/hip_runtime.h>

#define NPTS 4096
#define NQ   1024     // S
#define NB   16       // B
#define KNN  32
#define MROWS 524288  // B*S*K
#define FLT_MAX_ 3.402823466e+38f

typedef __attribute__((ext_vector_type(8))) _Float16 half8;
typedef __attribute__((ext_vector_type(4))) float f32x4;

// ---------- f16 helpers ----------
__device__ __forceinline__ unsigned cvt_pk_f16(float lo, float hi){
  auto v = __builtin_amdgcn_cvt_pkrtz(lo, hi);
  union { decltype(v) h; unsigned u; } cv; cv.h = v;
  return cv.u;
}

// normalize+relu 8 f16 channels via native packed-half fma/max
__device__ __forceinline__ half8 norm_frag_h(uint4 v, half8 sc, half8 sh){
  union { uint4 u4; half8 h8; } cv;
  cv.u4 = v;
  half8 r = cv.h8 * sc + sh;
  const half8 z8 = (half8)(_Float16)0.f;
  return __builtin_elementwise_max(r, z8);
}

// ---------- topk helpers (R16-proven) ----------
// PINNED distance: every add lives inside an explicit fmaf -> no contraction
// freedom -> bit-identical value at every call site (count/emit consistency).
__device__ __forceinline__ float distf(float4 pv, float qx, float qy, float qz, float s2){
  const float dot = fmaf(qx, pv.x, fmaf(qy, pv.y, qz * pv.z));
  return fmaf(-2.f, dot, s2 + pv.w);
}

__device__ __forceinline__ void ins5f(float d, float& c0, float& c1, float& c2,
                                      float& c3, float& c4){
  const float n0 = fminf(d, c0);
  const float n1 = __builtin_amdgcn_fmed3f(d, c0, c1);
  const float n2 = __builtin_amdgcn_fmed3f(d, c1, c2);
  const float n3 = __builtin_amdgcn_fmed3f(d, c2, c3);
  const float n4 = __builtin_amdgcn_fmed3f(d, c3, c4);
  c0 = n0; c1 = n1; c2 = n2; c3 = n3; c4 = n4;
}

__device__ __forceinline__ void ins5d(double pd, double& c0, double& c1, double& c2,
                                      double& c3, double& c4){
  const double t4 = fmin(c4, pd);
  const double n3 = fmin(c3, t4), x4 = fmax(c3, t4);
  const double n2 = fmin(c2, n3), x3 = fmax(c2, n3);
  const double n1 = fmin(c1, n2), x2 = fmax(c1, n2);
  const double n0 = fmin(c0, n1), x1 = fmax(c0, n1);
  c0 = n0; c1 = x1; c2 = x2; c3 = x3; c4 = x4;
}

__device__ __forceinline__ void scan5d(const float4* pbuf, int lane,
                                       float qx, float qy, float qz, float src2,
                                       unsigned long long skip,
                                       double& c0, double& c1, double& c2, double& c3, double& c4){
  for (int e = 0; e < 64; ++e){
    if ((skip >> e) & 1ull) continue;
    const int j = (e << 6) | lane;
    const float d = distf(pbuf[j], qx, qy, qz, src2);
    const unsigned long long uu =
        (unsigned long long)__double_as_longlong((double)d) | (unsigned)j;
    ins5d(__longlong_as_double((long long)uu), c0, c1, c2, c3, c4);
  }
}

// COLD exact fallback — noinline keeps the hot loop small. All selection state
// is internal (by-value args in, global writes out) -> no R6 spill trap.
__device__ __noinline__ void extract_exact(const float4* pbuf, int lane,
                                           float qx, float qy, float qz, float src2,
                                           int qidx, int* idx_out){
  const double DINF = __builtin_inf();
  double c0 = DINF, c1 = DINF, c2 = DINF, c3 = DINF, c4 = DINF;
  scan5d(pbuf, lane, qx, qy, qz, src2, 0ull, c0, c1, c2, c3, c4);
  unsigned long long skip = 0ull;
  int nc = 5;
  int win = 0;
  #pragma unroll 1
  for (int it = 0; it < KNN; ++it){
    double w = c0;
    #pragma unroll
    for (int m = 32; m >= 1; m >>= 1)
      w = fmin(w, __shfl_xor(w, m, 64));
    if (lane == it) win = (int)((unsigned)__double_as_longlong(w) & 0xFFFu);
    if (c0 == w){
      const unsigned lo = (unsigned)__double_as_longlong(c0);
      skip |= 1ull << ((lo >> 6) & 63u);
      c0 = c1; c1 = c2; c2 = c3; c3 = c4; c4 = DINF;
      if (--nc == 0){
        c0 = c1 = c2 = c3 = c4 = DINF;
        scan5d(pbuf, lane, qx, qy, qz, src2, skip, c0, c1, c2, c3, c4);
        nc = 5;
      }
    }
  }
  if (lane < KNN) idx_out[qidx * KNN + lane] = win;
}

// COLD single-query emit (used when not all 4 queries are emit-eligible)
__device__ __noinline__ int emit32(const float4* pbuf, int lane,
                                   float qx, float qy, float qz, float src2,
                                   float T, int* outq){
  int base = 0;
  const unsigned long long below = (1ull << lane) - 1ull;
  for (int e = 0; e < 64; ++e){
    const int j = (e << 6) | lane;
    const float d = distf(pbuf[j], qx, qy, qz, src2);
    const bool hit = d < T;
    const unsigned long long m = __ballot(hit);
    if (hit){
      const int slot = base + __popcll(m & below);
      if (slot < KNN) outq[slot] = j;
    }
    base += __popcll(m);
  }
  return base;
}

// wave-wide f32 min/max
__device__ __forceinline__ float wave_minf(float v){
  #pragma unroll
  for (int m = 32; m >= 1; m >>= 1) v = fminf(v, __shfl_xor(v, m, 64));
  return v;
}
__device__ __forceinline__ float wave_maxf(float v){
  #pragma unroll
  for (int m = 32; m >= 1; m >>= 1) v = fmaxf(v, __shfl_xor(v, m, 64));
  return v;
}

// ---------- Kernel 1: top-K=32 NN via f32 top-5 + f32 threshold bisection ----------
// FOUR queries per wave (ILP over TLP): 512 thr x 8 waves, 32 queries/block.
__global__ __launch_bounds__(512) void topk_kernel(const float* __restrict__ xyz,
                                                   int* __restrict__ idx_out,
                                                   float* __restrict__ statsacc){
  __shared__ float4 pbuf[NPTS];          // 64 KB: x, y, z, |p|^2
  const int tid = threadIdx.x;
  if (blockIdx.x == 0){
    for (int i = tid; i < 2048; i += 512) statsacc[i] = 0.f;
  }

  const int b = blockIdx.x >> 5;         // 32 blocks per batch, 32 queries/block
  const float* xb = xyz + (size_t)b * NPTS * 3;
  for (int p = tid; p < NPTS; p += 512){
    const float x = xb[3*p + 0], y = xb[3*p + 1], z = xb[3*p + 2];
    pbuf[p] = make_float4(x, y, z, fmaf(x, x, fmaf(y, y, z*z)));
  }
  __syncthreads();

  const int wv    = tid >> 6;
  const int lane  = tid & 63;
  const int qbase = blockIdx.x * 32 + wv*4;

  float qx[4], qy[4], qz[4], s2[4];
  #pragma unroll
  for (int t = 0; t < 4; ++t){
    const float4 qp = pbuf[(qbase + t) & (NQ - 1)];
    qx[t] = qp.x; qy[t] = qp.y; qz[t] = qp.z; s2[t] = qp.w;
  }

  // phase 1: per-lane f32 top-5 for 4 queries, shared point loads
  float c[4][5];
  #pragma unroll
  for (int t = 0; t < 4; ++t)
    #pragma unroll
    for (int i = 0; i < 5; ++i) c[t][i] = FLT_MAX_;

  for (int e = 0; e < 64; ++e){
    const int j = (e << 6) | lane;
    const float4 pv = pbuf[j];
    #pragma unroll
    for (int t = 0; t < 4; ++t){
      const float d = distf(pv, qx[t], qy[t], qz[t], s2[t]);
      ins5f(d, c[t][0], c[t][1], c[t][2], c[t][3], c[t][4]);
    }
  }

  // data-driven bisection bounds (R23-proven): cnt(lo)=0 < 32 <= cnt(hi)=320
  float lo[4], hi[4], T[4];
  bool done[4];
  #pragma unroll
  for (int t = 0; t < 4; ++t){
    lo[t] = wave_minf(c[t][0]);
    float h = wave_maxf(c[t][4]);
    hi[t] = fmaf(fabsf(h), 1e-6f, h) + 1e-30f;
    T[t] = 0.f; done[t] = false;
  }
  #pragma unroll 1
  for (int bi = 0; bi < 32 && !(done[0] && done[1] && done[2] && done[3]); ++bi){
    #pragma unroll
    for (int t = 0; t < 4; ++t){
      if (!done[t]){
        const float g = 0.5f*(lo[t] + hi[t]);
        const int cnt = __popcll(__ballot(c[t][0] < g)) + __popcll(__ballot(c[t][1] < g))
                      + __popcll(__ballot(c[t][2] < g)) + __popcll(__ballot(c[t][3] < g))
                      + __popcll(__ballot(c[t][4] < g));
        if (cnt >= KNN){ hi[t] = g; if (cnt == KNN){ T[t] = g; done[t] = true; } }
        else lo[t] = g;
      }
    }
  }

  bool ok[4];
  #pragma unroll
  for (int t = 0; t < 4; ++t)
    ok[t] = done[t] && !__any(c[t][4] < T[t]);

  if (ok[0] && ok[1] && ok[2] && ok[3]){
    // HOT quad emit: one LDS read per point serves all 4 queries
    int base[4] = {0, 0, 0, 0};
    const unsigned long long below = (1ull << lane) - 1ull;
    for (int e = 0; e < 64; ++e){
      const int j = (e << 6) | lane;
      const float4 pv = pbuf[j];
      #pragma unroll
      for (int t = 0; t < 4; ++t){
        const float d = distf(pv, qx[t], qy[t], qz[t], s2[t]);
        const bool hit = d < T[t];
        const unsigned long long m = __ballot(hit);
        if (hit){
          const int slot = base[t] + __popcll(m & below);
          if (slot < KNN) idx_out[(size_t)(qbase + t) * KNN + slot] = j;
        }
        base[t] += __popcll(m);
      }
    }
    #pragma unroll
    for (int t = 0; t < 4; ++t) ok[t] = (base[t] == KNN);
  } else {
    #pragma unroll
    for (int t = 0; t < 4; ++t)
      if (ok[t])
        ok[t] = (emit32(pbuf, lane, qx[t], qy[t], qz[t], s2[t], T[t],
                        idx_out + (size_t)(qbase + t) * KNN) == KNN);
  }
  #pragma unroll
  for (int t = 0; t < 4; ++t)
    if (!ok[t])
      extract_exact(pbuf, lane, qx[t], qy[t], qz[t], s2[t], qbase + t, idx_out);
}

// ---------- Layer 0: gather + concat + SWAPPED MFMA f16 GEMM, 512 blocks x 4 tiles ----------
__global__ __launch_bounds__(256) void l0_mfma(const float* __restrict__ xyz,
                                               const float* __restrict__ pts,
                                               const int*   __restrict__ idxbuf,
                                               const float* __restrict__ W,     // (64,67)
                                               const float* __restrict__ bias,  // (64)
                                               unsigned short* __restrict__ hout,
                                               float* __restrict__ acc){        // 4 x 128
  __shared__ short lds[256*104];
  __shared__ float sacc[128];
  const int tid = threadIdx.x;
  if (tid < 128) sacc[tid] = 0.f;
  const int lane = tid & 63, wv = tid >> 6;
  const int m16 = lane & 15, kg = lane >> 4;

  half8  Wf[4][3];
  f32x4  bl4[4];
  for (int cg = 0; cg < 4; ++cg){
    bl4[cg] = *(const f32x4*)(bias + cg*16 + kg*4);
    const int n = cg*16 + m16;
    for (int ks = 0; ks < 3; ++ks){
      half8 t;
      #pragma unroll
      for (int i = 0; i < 8; ++i){
        const int k = ks*32 + kg*8 + i;
        float wv_ = 0.f;
        if (k < 64) wv_ = W[n*67 + 3 + k];
        else if (k < 67) wv_ = W[n*67 + (k - 64)];
        t[i] = (_Float16)wv_;
      }
      Wf[cg][ks] = t;
    }
  }

  f32x4 zero4 = {0.f, 0.f, 0.f, 0.f};
  f32x4 sA[4] = {zero4, zero4, zero4, zero4};
  f32x4 qA[4] = {zero4, zero4, zero4, zero4};

  for (int tt = 0; tt < 4; ++tt){
    const int tilebase = (blockIdx.x*4 + tt)*256;
    {
      const int row = tilebase + tid;
      const int rowq = row >> 5;
      const int b = rowq >> 10, s = rowq & 1023;
      const int j = idxbuf[row];
      const float4* p4 = (const float4*)(pts + ((size_t)b*NPTS + j)*64);
      short* myrow = lds + tid*104;
      #pragma unroll
      for (int u = 0; u < 8; ++u){
        float4 x = p4[2*u], y = p4[2*u+1];
        uint4 o;
        o.x = cvt_pk_f16(x.x, x.y);
        o.y = cvt_pk_f16(x.z, x.w);
        o.z = cvt_pk_f16(y.x, y.y);
        o.w = cvt_pk_f16(y.z, y.w);
        *(uint4*)(myrow + u*8) = o;
      }
      const float* pj = xyz + ((size_t)b*NPTS + j)*3;
      const float* ps = xyz + ((size_t)b*NPTS + s)*3;
      uint4 z;
      z.x = cvt_pk_f16(pj[0]-ps[0], pj[1]-ps[1]);
      z.y = cvt_pk_f16(pj[2]-ps[2], 0.f);
      z.z = 0u; z.w = 0u;
      *(uint4*)(myrow + 64) = z;
      uint4 zz; zz.x = zz.y = zz.z = zz.w = 0u;
      *(uint4*)(myrow + 72) = zz;
      *(uint4*)(myrow + 80) = zz;
      *(uint4*)(myrow + 88) = zz;
    }
    __syncthreads();

    const int rowbase = tilebase + wv*64;
    for (int rt = 0; rt < 4; ++rt){
      const short* ar = lds + (wv*64 + rt*16 + m16)*104;
      half8 x0 = *(const half8*)(ar + kg*8);
      half8 x1 = *(const half8*)(ar + 32 + kg*8);
      half8 x2 = *(const half8*)(ar + 64 + kg*8);
      const size_t rbase = (size_t)(rowbase + rt*16 + m16) * 64;
      #pragma unroll
      for (int cg = 0; cg < 4; ++cg){
        f32x4 c = bl4[cg];
        c = __builtin_amdgcn_mfma_f32_16x16x32_f16(Wf[cg][0], x0, c, 0, 0, 0);
        c = __builtin_amdgcn_mfma_f32_16x16x32_f16(Wf[cg][1], x1, c, 0, 0, 0);
        c = __builtin_amdgcn_mfma_f32_16x16x32_f16(Wf[cg][2], x2, c, 0, 0, 0);
        sA[cg] += c; qA[cg] += c*c;
        uint2 o;
        o.x = cvt_pk_f16(c[0], c[1]);
        o.y = cvt_pk_f16(c[2], c[3]);
        *(uint2*)(hout + rbase + cg*16 + kg*4) = o;
      }
    }
    __syncthreads();   // all reads done before next tile's staging overwrites
  }

  #pragma unroll
  for (int cg = 0; cg < 4; ++cg)
    #pragma unroll
    for (int m = 1; m <= 8; m <<= 1)
      #pragma unroll
      for (int t = 0; t < 4; ++t){
        sA[cg][t] += __shfl_xor(sA[cg][t], m, 64);
        qA[cg][t] += __shfl_xor(qA[cg][t], m, 64);
      }
  if (m16 == 0){
    #pragma unroll
    for (int cg = 0; cg < 4; ++cg)
      #pragma unroll
      for (int t = 0; t < 4; ++t){
        atomicAdd(&sacc[cg*16 + kg*4 + t], sA[cg][t]);
        atomicAdd(&sacc[64 + cg*16 + kg*4 + t], qA[cg][t]);
      }
  }
  __syncthreads();
  if (tid < 128) atomicAdd(&acc[(blockIdx.x & 3)*128 + tid], sacc[tid]);
}

// ---------- Layer 1: in-kernel ss0 (4-bank sum) + packed-f16 norm+relu + SWAPPED MFMA f16 ----------
// 512 blocks x 4 row-tiles.
__global__ __launch_bounds__(256) void l1_mfma(const unsigned* __restrict__ hin,
                                               const float* __restrict__ acc0,  // 4 x 128
                                               const float* __restrict__ g,
                                               const float* __restrict__ be,
                                               const float* __restrict__ W,     // (64,64)
                                               const float* __restrict__ bias,  // (64)
                                               unsigned short* __restrict__ hout,
                                               float* __restrict__ acc1){       // 4 x 128
  __shared__ float ssl[128];
  __shared__ float sacc[128];
  const int tid = threadIdx.x;
  if (tid < 128) sacc[tid] = 0.f;
  if (tid < 64){
    float s = 0.f, q = 0.f;
    #pragma unroll
    for (int bnk = 0; bnk < 4; ++bnk){
      s += acc0[bnk*128 + tid];
      q += acc0[bnk*128 + 64 + tid];
    }
    const float invM = 1.f / (float)MROWS;
    const float mean = s * invM;
    const float var  = q * invM - mean*mean;
    const float scale = g[tid] * rsqrtf(var + 1e-5f);
    ssl[2*tid + 0] = scale;
    ssl[2*tid + 1] = be[tid] - mean * scale;
  }
  __syncthreads();

  const int lane = tid & 63, wv = tid >> 6;
  const int m16 = lane & 15, kg = lane >> 4;

  half8 scl8[2], shf8[2];
  #pragma unroll
  for (int s2 = 0; s2 < 2; ++s2)
    #pragma unroll
    for (int i = 0; i < 8; ++i){
      const int c = s2*32 + kg*8 + i;
      scl8[s2][i] = (_Float16)ssl[2*c + 0];
      shf8[s2][i] = (_Float16)ssl[2*c + 1];
    }

  half8  Wf[4][2];
  f32x4  bl4[4];
  for (int cg = 0; cg < 4; ++cg){
    bl4[cg] = *(const f32x4*)(bias + cg*16 + kg*4);
    const int n = cg*16 + m16;
    #pragma unroll
    for (int s2 = 0; s2 < 2; ++s2){
      half8 t;
      #pragma unroll
      for (int i = 0; i < 8; ++i)
        t[i] = (_Float16)W[n*64 + s2*32 + kg*8 + i];
      Wf[cg][s2] = t;
    }
  }

  f32x4 zero4 = {0.f, 0.f, 0.f, 0.f};
  f32x4 sA[4] = {zero4, zero4, zero4, zero4};
  f32x4 qA[4] = {zero4, zero4, zero4, zero4};

  for (int tt = 0; tt < 4; ++tt){
    const int rowbase = (blockIdx.x*4 + tt)*256 + wv*64;
    for (int rt = 0; rt < 4; ++rt){
      const int arow = rowbase + rt*16 + m16;
      const uint4* pr = (const uint4*)hin + (size_t)arow*8;
      uint4 v0 = pr[kg];
      uint4 v1 = pr[4 + kg];
      half8 x0 = norm_frag_h(v0, scl8[0], shf8[0]);
      half8 x1 = norm_frag_h(v1, scl8[1], shf8[1]);
      const size_t rbase = (size_t)arow * 64;
      #pragma unroll
      for (int cg = 0; cg < 4; ++cg){
        f32x4 c = bl4[cg];
        c = __builtin_amdgcn_mfma_f32_16x16x32_f16(Wf[cg][0], x0, c, 0, 0, 0);
        c = __builtin_amdgcn_mfma_f32_16x16x32_f16(Wf[cg][1], x1, c, 0, 0, 0);
        sA[cg] += c; qA[cg] += c*c;
        uint2 o;
        o.x = cvt_pk_f16(c[0], c[1]);
        o.y = cvt_pk_f16(c[2], c[3]);
        *(uint2*)(hout + rbase + cg*16 + kg*4) = o;
      }
    }
  }
  #pragma unroll
  for (int cg = 0; cg < 4; ++cg)
    #pragma unroll
    for (int m = 1; m <= 8; m <<= 1)
      #pragma unroll
      for (int t = 0; t < 4; ++t){
        sA[cg][t] += __shfl_xor(sA[cg][t], m, 64);
        qA[cg][t] += __shfl_xor(qA[cg][t], m, 64);
      }
  if (m16 == 0){
    #pragma unroll
    for (int cg = 0; cg < 4; ++cg)
      #pragma unroll
      for (int t = 0; t < 4; ++t){
        atomicAdd(&sacc[cg*16 + kg*4 + t], sA[cg][t]);
        atomicAdd(&sacc[64 + cg*16 + kg*4 + t], qA[cg][t]);
      }
  }
  __syncthreads();
  if (tid < 128) atomicAdd(&acc1[(blockIdx.x & 3)*128 + tid], sacc[tid]);
}

// ---------- Layer 2 FUSED: in-kernel ss1 (4-bank) + packed-f16 norm + f16 GEMM 64->128 + stats + max/min ----------
// 512 blocks x 4 row-tiles.
__global__ __launch_bounds__(256) void l2_fused(const unsigned* __restrict__ hin,
                                                const float* __restrict__ acc1,  // 4 x 128
                                                const float* __restrict__ g,
                                                const float* __restrict__ be,
                                                const float* __restrict__ W,     // (128,64)
                                                const float* __restrict__ bias,  // (128)
                                                float* __restrict__ maxb,        // (16384,128)
                                                float* __restrict__ minb,        // (16384,128)
                                                float* __restrict__ acc2){       // 4 x 256
  __shared__ float ssl[128];
  __shared__ float sacc[256];
  const int tid = threadIdx.x;
  sacc[tid] = 0.f;
  if (tid < 64){
    float s = 0.f, q = 0.f;
    #pragma unroll
    for (int bnk = 0; bnk < 4; ++bnk){
      s += acc1[bnk*128 + tid];
      q += acc1[bnk*128 + 64 + tid];
    }
    const float invM = 1.f / (float)MROWS;
    const float mean = s * invM;
    const float var  = q * invM - mean*mean;
    const float scale = g[tid] * rsqrtf(var + 1e-5f);
    ssl[2*tid + 0] = scale;
    ssl[2*tid + 1] = be[tid] - mean * scale;
  }
  __syncthreads();

  const int lane = tid & 63, wv = tid >> 6;
  const int m16 = lane & 15, kg = lane >> 4;

  half8 scl8[2], shf8[2];
  #pragma unroll
  for (int s2 = 0; s2 < 2; ++s2)
    #pragma unroll
    for (int i = 0; i < 8; ++i){
      const int c = s2*32 + kg*8 + i;
      scl8[s2][i] = (_Float16)ssl[2*c + 0];
      shf8[s2][i] = (_Float16)ssl[2*c + 1];
    }

  half8 Bf[8][2];
  float bl[8];
  for (int ocb = 0; ocb < 8; ++ocb){
    const int n = ocb*16 + m16;
    bl[ocb] = bias[n];
    #pragma unroll
    for (int s2 = 0; s2 < 2; ++s2){
      half8 t;
      #pragma unroll
      for (int i = 0; i < 8; ++i)
        t[i] = (_Float16)W[n*64 + s2*32 + kg*8 + i];
      Bf[ocb][s2] = t;
    }
  }

  float sA[8], qA[8];
  #pragma unroll
  for (int o = 0; o < 8; ++o){ sA[o] = 0.f; qA[o] = 0.f; }

  for (int tt = 0; tt < 4; ++tt){
    const int rowbase = (blockIdx.x*4 + tt)*256 + wv*64;   // 2 queries per wave
    float mx[2][8], mn[2][8];
    #pragma unroll
    for (int o = 0; o < 8; ++o){
      mx[0][o] = -FLT_MAX_; mx[1][o] = -FLT_MAX_;
      mn[0][o] =  FLT_MAX_; mn[1][o] =  FLT_MAX_;
    }
    #pragma unroll
    for (int rt = 0; rt < 4; ++rt){
      const int qs = rt >> 1;
      const int arow = rowbase + rt*16 + m16;
      const uint4* pr = (const uint4*)hin + (size_t)arow*8;
      uint4 v0 = pr[kg];
      uint4 v1 = pr[4 + kg];
      half8 a0 = norm_frag_h(v0, scl8[0], shf8[0]);
      half8 a1 = norm_frag_h(v1, scl8[1], shf8[1]);
      #pragma unroll
      for (int ocb = 0; ocb < 8; ++ocb){
        f32x4 c = {bl[ocb], bl[ocb], bl[ocb], bl[ocb]};
        c = __builtin_amdgcn_mfma_f32_16x16x32_f16(a0, Bf[ocb][0], c, 0, 0, 0);
        c = __builtin_amdgcn_mfma_f32_16x16x32_f16(a1, Bf[ocb][1], c, 0, 0, 0);
        #pragma unroll
        for (int r = 0; r < 4; ++r){
          const float hv = c[r];
          sA[ocb] += hv; qA[ocb] += hv*hv;
          mx[qs][ocb] = fmaxf(mx[qs][ocb], hv);
          mn[qs][ocb] = fminf(mn[qs][ocb], hv);
        }
      }
    }
    const int qa = rowbase >> 5;
    #pragma unroll
    for (int qs = 0; qs < 2; ++qs)
      #pragma unroll
      for (int ocb = 0; ocb < 8; ++ocb){
        float a = mx[qs][ocb], b = mn[qs][ocb];
        a = fmaxf(a, __shfl_xor(a, 16, 64)); a = fmaxf(a, __shfl_xor(a, 32, 64));
        b = fminf(b, __shfl_xor(b, 16, 64)); b = fminf(b, __shfl_xor(b, 32, 64));
        if (kg == 0){
          maxb[(size_t)(qa + qs)*128 + ocb*16 + m16] = a;
          minb[(size_t)(qa + qs)*128 + ocb*16 + m16] = b;
        }
      }
  }

  #pragma unroll
  for (int ocb = 0; ocb < 8; ++ocb){
    float s = sA[ocb], q = qA[ocb];
    s += __shfl_xor(s, 16, 64); s += __shfl_xor(s, 32, 64);
    q += __shfl_xor(q, 16, 64); q += __shfl_xor(q, 32, 64);
    if (kg == 0){
      atomicAdd(&sacc[ocb*16 + m16], s);
      atomicAdd(&sacc[128 + ocb*16 + m16], q);
    }
  }
  __syncthreads();
  atomicAdd(&acc2[(blockIdx.x & 3)*256 + tid], sacc[tid]);
}

// ---------- Final: in-kernel ss2 (4-bank); out = relu(scale*(scale>=0?max:min)+shift) ----------
__global__ __launch_bounds__(256) void final_kernel(const float* __restrict__ xyz,
                                                    const float* __restrict__ maxb,
                                                    const float* __restrict__ minb,
                                                    const float* __restrict__ acc2, // 4 x 256
                                                    const float* __restrict__ g,
                                                    const float* __restrict__ be,
                                                    float* __restrict__ out){
  __shared__ float ssl[256];
  const int tid = threadIdx.x;
  if (tid < 128){
    float s = 0.f, q = 0.f;
    #pragma unroll
    for (int bnk = 0; bnk < 4; ++bnk){
      s += acc2[bnk*256 + tid];
      q += acc2[bnk*256 + 128 + tid];
    }
    const float invM = 1.f / (float)MROWS;
    const float mean = s * invM;
    const float var  = q * invM - mean*mean;
    const float scale = g[tid] * rsqrtf(var + 1e-5f);
    ssl[2*tid + 0] = scale;
    ssl[2*tid + 1] = be[tid] - mean * scale;
  }
  __syncthreads();

  const int q = blockIdx.x * 4 + (tid >> 6);
  const int p = tid & 63;
  const float sc0 = ssl[4*p + 0], sh0 = ssl[4*p + 1];
  const float sc1 = ssl[4*p + 2], sh1 = ssl[4*p + 3];
  const float2 mxv = ((const float2*)(maxb + (size_t)q*128))[p];
  const float2 mnv = ((const float2*)(minb + (size_t)q*128))[p];
  const float h0v = (sc0 >= 0.f) ? mxv.x : mnv.x;
  const float h1v = (sc1 >= 0.f) ? mxv.y : mnv.y;
  float2 r;
  r.x = fmaxf(fmaf(sc0, h0v, sh0), 0.f);
  r.y = fmaxf(fmaf(sc1, h1v, sh1), 0.f);
  ((float2*)(out + (size_t)NB*NQ*3))[(size_t)q*64 + p] = r;
  if (p < 3){
    const int b_ = q >> 10, s = q & 1023;
    out[(size_t)q*3 + p] = xyz[((size_t)b_ * NPTS + s)*3 + p];
  }
}

// ---------- host ----------
extern "C" void kernel_launch(void* const* d_in, const int* in_sizes, int n_in,
                              void* d_out, int out_size, void* d_ws, size_t ws_size,
                              hipStream_t stream){
  (void)in_sizes; (void)n_in; (void)out_size; (void)ws_size;
  const float* xyz = (const float*)d_in[0];
  const float* pts = (const float*)d_in[1];
  const float* W0  = (const float*)d_in[2];
  const float* b0  = (const float*)d_in[3];
  const float* g0  = (const float*)d_in[4];
  const float* be0 = (const float*)d_in[5];
  const float* W1  = (const float*)d_in[6];
  const float* b1  = (const float*)d_in[7];
  const float* g1  = (const float*)d_in[8];
  const float* be1 = (const float*)d_in[9];
  const float* W2  = (const float*)d_in[10];
  const float* b2  = (const float*)d_in[11];
  const float* g2  = (const float*)d_in[12];
  const float* be2 = (const float*)d_in[13];

  // workspace: idx 2MB | acc 2048f (acc0 4x128 | acc1 4x128 | acc2 4x256) | h0 64MB | h1 64MB
  char* ws = (char*)d_ws;
  int*   idx = (int*)ws;
  float* acc = (float*)(ws + 2097152);
  unsigned* h0 = (unsigned*)(ws + 2097152 + 8192);
  unsigned* h1 = (unsigned*)(ws + 2097152 + 8192 + 67108864);
  float* maxb = (float*)h0;                    // reuses h0 (dead after l1)
  float* minb = maxb + (size_t)16384*128;
  float* out = (float*)d_out;

  float* acc0 = acc, *acc1 = acc + 512, *acc2 = acc + 1024;

  topk_kernel<<<512, 512, 0, stream>>>(xyz, idx, acc);
  l0_mfma<<<512, 256, 0, stream>>>(xyz, pts, idx, W0, b0, (unsigned short*)h0, acc0);
  l1_mfma<<<512, 256, 0, stream>>>(h0, acc0, g0, be0, W1, b1, (unsigned short*)h1, acc1);
  l2_fused<<<512, 256, 0, stream>>>(h1, acc1, g1, be1, W2, b2, maxb, minb, acc2);
  final_kernel<<<4096, 256, 0, stream>>>(xyz, maxb, minb, acc2, g2, be2, out);
}

// Round 25
// 193.999 us; speedup vs baseline: 1.1208x; 1.1208x over previous
//
#include <hip/hip_runtime.h>

#define NPTS 4096
#define NQ   1024     // S
#define NB   16       // B
#define KNN  32
#define MROWS 524288  // B*S*K
#define FLT_MAX_ 3.402823466e+38f

typedef __attribute__((ext_vector_type(8))) _Float16 half8;
typedef __attribute__((ext_vector_type(4))) float f32x4;

// ---------- f16 helpers ----------
__device__ __forceinline__ unsigned cvt_pk_f16(float lo, float hi){
  auto v = __builtin_amdgcn_cvt_pkrtz(lo, hi);
  union { decltype(v) h; unsigned u; } cv; cv.h = v;
  return cv.u;
}

// normalize+relu 8 f16 channels via native packed-half fma/max
__device__ __forceinline__ half8 norm_frag_h(uint4 v, half8 sc, half8 sh){
  union { uint4 u4; half8 h8; } cv;
  cv.u4 = v;
  half8 r = cv.h8 * sc + sh;
  const half8 z8 = (half8)(_Float16)0.f;
  return __builtin_elementwise_max(r, z8);
}

// ---------- topk helpers (R16-proven) ----------
// PINNED distance: every add lives inside an explicit fmaf -> no contraction
// freedom -> bit-identical value at every call site (count/emit consistency).
__device__ __forceinline__ float distf(float4 pv, float qx, float qy, float qz, float s2){
  const float dot = fmaf(qx, pv.x, fmaf(qy, pv.y, qz * pv.z));
  return fmaf(-2.f, dot, s2 + pv.w);
}

// payload-free f32 top-6 insert (all levels read OLD values; 1-deep, full-rate)
__device__ __forceinline__ void ins6f(float d, float& c0, float& c1, float& c2,
                                      float& c3, float& c4, float& c5){
  const float n0 = fminf(d, c0);
  const float n1 = __builtin_amdgcn_fmed3f(d, c0, c1);
  const float n2 = __builtin_amdgcn_fmed3f(d, c1, c2);
  const float n3 = __builtin_amdgcn_fmed3f(d, c2, c3);
  const float n4 = __builtin_amdgcn_fmed3f(d, c3, c4);
  const float n5 = __builtin_amdgcn_fmed3f(d, c4, c5);
  c0 = n0; c1 = n1; c2 = n2; c3 = n3; c4 = n4; c5 = n5;
}

__device__ __forceinline__ void ins5d(double pd, double& c0, double& c1, double& c2,
                                      double& c3, double& c4){
  const double t4 = fmin(c4, pd);
  const double n3 = fmin(c3, t4), x4 = fmax(c3, t4);
  const double n2 = fmin(c2, n3), x3 = fmax(c2, n3);
  const double n1 = fmin(c1, n2), x2 = fmax(c1, n2);
  const double n0 = fmin(c0, n1), x1 = fmax(c0, n1);
  c0 = n0; c1 = x1; c2 = x2; c3 = x3; c4 = x4;
}

__device__ __forceinline__ void scan5d(const float4* pbuf, int lane,
                                       float qx, float qy, float qz, float src2,
                                       unsigned long long skip,
                                       double& c0, double& c1, double& c2, double& c3, double& c4){
  for (int e = 0; e < 64; ++e){
    if ((skip >> e) & 1ull) continue;
    const int j = (e << 6) | lane;
    const float d = distf(pbuf[j], qx, qy, qz, src2);
    const unsigned long long uu =
        (unsigned long long)__double_as_longlong((double)d) | (unsigned)j;
    ins5d(__longlong_as_double((long long)uu), c0, c1, c2, c3, c4);
  }
}

// COLD exact fallback — noinline keeps the hot loop small. All selection state
// is internal (by-value args in, global writes out) -> no R6 spill trap.
__device__ __noinline__ void extract_exact(const float4* pbuf, int lane,
                                           float qx, float qy, float qz, float src2,
                                           int qidx, int* idx_out){
  const double DINF = __builtin_inf();
  double c0 = DINF, c1 = DINF, c2 = DINF, c3 = DINF, c4 = DINF;
  scan5d(pbuf, lane, qx, qy, qz, src2, 0ull, c0, c1, c2, c3, c4);
  unsigned long long skip = 0ull;
  int nc = 5;
  int win = 0;
  #pragma unroll 1
  for (int it = 0; it < KNN; ++it){
    double w = c0;
    #pragma unroll
    for (int m = 32; m >= 1; m >>= 1)
      w = fmin(w, __shfl_xor(w, m, 64));
    if (lane == it) win = (int)((unsigned)__double_as_longlong(w) & 0xFFFu);
    if (c0 == w){
      const unsigned lo = (unsigned)__double_as_longlong(c0);
      skip |= 1ull << ((lo >> 6) & 63u);
      c0 = c1; c1 = c2; c2 = c3; c3 = c4; c4 = DINF;
      if (--nc == 0){
        c0 = c1 = c2 = c3 = c4 = DINF;
        scan5d(pbuf, lane, qx, qy, qz, src2, skip, c0, c1, c2, c3, c4);
        nc = 5;
      }
    }
  }
  if (lane < KNN) idx_out[qidx * KNN + lane] = win;
}

// COLD single-query emit (only when exactly one query is emit-eligible)
__device__ __noinline__ int emit32(const float4* pbuf, int lane,
                                   float qx, float qy, float qz, float src2,
                                   float T, int* outq){
  int base = 0;
  const unsigned long long below = (1ull << lane) - 1ull;
  for (int e = 0; e < 64; ++e){
    const int j = (e << 6) | lane;
    const float d = distf(pbuf[j], qx, qy, qz, src2);
    const bool hit = d < T;
    const unsigned long long m = __ballot(hit);
    if (hit){
      const int slot = base + __popcll(m & below);
      if (slot < KNN) outq[slot] = j;
    }
    base += __popcll(m);
  }
  return base;
}

// HOT dual-query emit: ONE LDS read per point serves both queries
__device__ __forceinline__ int2 emit32_dual(const float4* pbuf, int lane,
                                            float axq, float ayq, float azq, float src2A,
                                            float bxq, float byq, float bzq, float src2B,
                                            float TA, float TB, int* outA, int* outB){
  int baseA = 0, baseB = 0;
  const unsigned long long below = (1ull << lane) - 1ull;
  for (int e = 0; e < 64; ++e){
    const int j = (e << 6) | lane;
    const float4 pv = pbuf[j];
    const float dA = distf(pv, axq, ayq, azq, src2A);
    const float dB = distf(pv, bxq, byq, bzq, src2B);
    const bool hA = dA < TA;
    const bool hB = dB < TB;
    const unsigned long long mA = __ballot(hA);
    const unsigned long long mB = __ballot(hB);
    if (hA){
      const int slot = baseA + __popcll(mA & below);
      if (slot < KNN) outA[slot] = j;
    }
    if (hB){
      const int slot = baseB + __popcll(mB & below);
      if (slot < KNN) outB[slot] = j;
    }
    baseA += __popcll(mA);
    baseB += __popcll(mB);
  }
  return make_int2(baseA, baseB);
}

// wave-wide f32 min/max
__device__ __forceinline__ float wave_minf(float v){
  #pragma unroll
  for (int m = 32; m >= 1; m >>= 1) v = fminf(v, __shfl_xor(v, m, 64));
  return v;
}
__device__ __forceinline__ float wave_maxf(float v){
  #pragma unroll
  for (int m = 32; m >= 1; m >>= 1) v = fmaxf(v, __shfl_xor(v, m, 64));
  return v;
}

// ---------- Kernel 1: top-K=32 NN via f32 top-6 + f32 threshold bisection ----------
// Top-6 cache cuts the exact-fallback rate ~12x (straggler-tail reduction).
__global__ __launch_bounds__(1024) void topk_kernel(const float* __restrict__ xyz,
                                                    int* __restrict__ idx_out,
                                                    float* __restrict__ statsacc){
  __shared__ float4 pbuf[NPTS];          // 64 KB: x, y, z, |p|^2
  const int tid = threadIdx.x;
  if (blockIdx.x == 0){
    statsacc[tid] = 0.f;
    statsacc[tid + 1024] = 0.f;
  }

  const int b = blockIdx.x >> 5;         // 32 blocks per batch, 32 queries/block
  const float* xb = xyz + (size_t)b * NPTS * 3;
  for (int p = tid; p < NPTS; p += 1024){
    const float x = xb[3*p + 0], y = xb[3*p + 1], z = xb[3*p + 2];
    pbuf[p] = make_float4(x, y, z, fmaf(x, x, fmaf(y, y, z*z)));
  }
  __syncthreads();

  const int wv   = tid >> 6;
  const int lane = tid & 63;
  const int qA   = blockIdx.x * 32 + wv*2;
  const int qB   = qA + 1;
  const int sA_  = qA & (NQ - 1);
  const int sB_  = qB & (NQ - 1);

  const float4 qpA = pbuf[sA_];
  const float4 qpB = pbuf[sB_];
  const float axq = qpA.x, ayq = qpA.y, azq = qpA.z, src2A = qpA.w;
  const float bxq = qpB.x, byq = qpB.y, bzq = qpB.z, src2B = qpB.w;

  float a0 = FLT_MAX_, a1 = FLT_MAX_, a2 = FLT_MAX_, a3 = FLT_MAX_, a4 = FLT_MAX_, a5 = FLT_MAX_;
  float b0 = FLT_MAX_, b1 = FLT_MAX_, b2 = FLT_MAX_, b3 = FLT_MAX_, b4 = FLT_MAX_, b5 = FLT_MAX_;
  for (int e = 0; e < 64; ++e){
    const int j = (e << 6) | lane;
    const float4 pv = pbuf[j];
    const float dA = distf(pv, axq, ayq, azq, src2A);
    const float dB = distf(pv, bxq, byq, bzq, src2B);
    ins6f(dA, a0, a1, a2, a3, a4, a5);
    ins6f(dB, b0, b1, b2, b3, b4, b5);
  }

  // data-driven bisection bounds: cnt(lo)=0 < 32 <= cnt(hi)=384 on caches.
  // Any T in (k32,k33] yields the SAME emitted set -> speed-only change.
  float loA = wave_minf(a0), loB = wave_minf(b0);
  float hiA = wave_maxf(a5), hiB = wave_maxf(b5);
  hiA = fmaf(fabsf(hiA), 1e-6f, hiA) + 1e-30f;
  hiB = fmaf(fabsf(hiB), 1e-6f, hiB) + 1e-30f;
  float TA = 0.f, TB = 0.f;
  bool doneA = false, doneB = false;
  #pragma unroll 1
  for (int bi = 0; bi < 32 && !(doneA && doneB); ++bi){
    if (!doneA){
      const float g = 0.5f*(loA + hiA);
      const int cnt = __popcll(__ballot(a0 < g)) + __popcll(__ballot(a1 < g))
                    + __popcll(__ballot(a2 < g)) + __popcll(__ballot(a3 < g))
                    + __popcll(__ballot(a4 < g)) + __popcll(__ballot(a5 < g));
      if (cnt >= KNN){ hiA = g; if (cnt == KNN){ TA = g; doneA = true; } }
      else loA = g;
    }
    if (!doneB){
      const float g = 0.5f*(loB + hiB);
      const int cnt = __popcll(__ballot(b0 < g)) + __popcll(__ballot(b1 < g))
                    + __popcll(__ballot(b2 < g)) + __popcll(__ballot(b3 < g))
                    + __popcll(__ballot(b4 < g)) + __popcll(__ballot(b5 < g));
      if (cnt >= KNN){ hiB = g; if (cnt == KNN){ TB = g; doneB = true; } }
      else loB = g;
    }
  }

  // validity: no lane's whole cache below T (else an evicted 7th could be < T)
  bool okA = doneA && !__any(a5 < TA);
  bool okB = doneB && !__any(b5 < TB);
  if (okA && okB){
    const int2 c = emit32_dual(pbuf, lane, axq, ayq, azq, src2A,
                               bxq, byq, bzq, src2B, TA, TB,
                               idx_out + qA * KNN, idx_out + qB * KNN);
    okA = (c.x == KNN);
    okB = (c.y == KNN);
  } else {
    if (okA)
      okA = (emit32(pbuf, lane, axq, ayq, azq, src2A, TA, idx_out + qA * KNN) == KNN);
    if (okB)
      okB = (emit32(pbuf, lane, bxq, byq, bzq, src2B, TB, idx_out + qB * KNN) == KNN);
  }
  if (!okA) extract_exact(pbuf, lane, axq, ayq, azq, src2A, qA, idx_out);
  if (!okB) extract_exact(pbuf, lane, bxq, byq, bzq, src2B, qB, idx_out);
}

// ---------- Layer 0: gather + concat + SWAPPED MFMA f16 GEMM, 512 blocks x 4 tiles ----------
__global__ __launch_bounds__(256) void l0_mfma(const float* __restrict__ xyz,
                                               const float* __restrict__ pts,
                                               const int*   __restrict__ idxbuf,
                                               const float* __restrict__ W,     // (64,67)
                                               const float* __restrict__ bias,  // (64)
                                               unsigned short* __restrict__ hout,
                                               float* __restrict__ acc){        // 4 x 128
  __shared__ short lds[256*104];
  __shared__ float sacc[128];
  const int tid = threadIdx.x;
  if (tid < 128) sacc[tid] = 0.f;
  const int lane = tid & 63, wv = tid >> 6;
  const int m16 = lane & 15, kg = lane >> 4;

  half8  Wf[4][3];
  f32x4  bl4[4];
  for (int cg = 0; cg < 4; ++cg){
    bl4[cg] = *(const f32x4*)(bias + cg*16 + kg*4);
    const int n = cg*16 + m16;
    for (int ks = 0; ks < 3; ++ks){
      half8 t;
      #pragma unroll
      for (int i = 0; i < 8; ++i){
        const int k = ks*32 + kg*8 + i;
        float wv_ = 0.f;
        if (k < 64) wv_ = W[n*67 + 3 + k];
        else if (k < 67) wv_ = W[n*67 + (k - 64)];
        t[i] = (_Float16)wv_;
      }
      Wf[cg][ks] = t;
    }
  }

  f32x4 zero4 = {0.f, 0.f, 0.f, 0.f};
  f32x4 sA[4] = {zero4, zero4, zero4, zero4};
  f32x4 qA[4] = {zero4, zero4, zero4, zero4};

  for (int tt = 0; tt < 4; ++tt){
    const int tilebase = (blockIdx.x*4 + tt)*256;
    {
      const int row = tilebase + tid;
      const int rowq = row >> 5;
      const int b = rowq >> 10, s = rowq & 1023;
      const int j = idxbuf[row];
      const float4* p4 = (const float4*)(pts + ((size_t)b*NPTS + j)*64);
      short* myrow = lds + tid*104;
      #pragma unroll
      for (int u = 0; u < 8; ++u){
        float4 x = p4[2*u], y = p4[2*u+1];
        uint4 o;
        o.x = cvt_pk_f16(x.x, x.y);
        o.y = cvt_pk_f16(x.z, x.w);
        o.z = cvt_pk_f16(y.x, y.y);
        o.w = cvt_pk_f16(y.z, y.w);
        *(uint4*)(myrow + u*8) = o;
      }
      const float* pj = xyz + ((size_t)b*NPTS + j)*3;
      const float* ps = xyz + ((size_t)b*NPTS + s)*3;
      uint4 z;
      z.x = cvt_pk_f16(pj[0]-ps[0], pj[1]-ps[1]);
      z.y = cvt_pk_f16(pj[2]-ps[2], 0.f);
      z.z = 0u; z.w = 0u;
      *(uint4*)(myrow + 64) = z;
      uint4 zz; zz.x = zz.y = zz.z = zz.w = 0u;
      *(uint4*)(myrow + 72) = zz;
      *(uint4*)(myrow + 80) = zz;
      *(uint4*)(myrow + 88) = zz;
    }
    __syncthreads();

    const int rowbase = tilebase + wv*64;
    for (int rt = 0; rt < 4; ++rt){
      const short* ar = lds + (wv*64 + rt*16 + m16)*104;
      half8 x0 = *(const half8*)(ar + kg*8);
      half8 x1 = *(const half8*)(ar + 32 + kg*8);
      half8 x2 = *(const half8*)(ar + 64 + kg*8);
      const size_t rbase = (size_t)(rowbase + rt*16 + m16) * 64;
      #pragma unroll
      for (int cg = 0; cg < 4; ++cg){
        f32x4 c = bl4[cg];
        c = __builtin_amdgcn_mfma_f32_16x16x32_f16(Wf[cg][0], x0, c, 0, 0, 0);
        c = __builtin_amdgcn_mfma_f32_16x16x32_f16(Wf[cg][1], x1, c, 0, 0, 0);
        c = __builtin_amdgcn_mfma_f32_16x16x32_f16(Wf[cg][2], x2, c, 0, 0, 0);
        sA[cg] += c; qA[cg] += c*c;
        uint2 o;
        o.x = cvt_pk_f16(c[0], c[1]);
        o.y = cvt_pk_f16(c[2], c[3]);
        *(uint2*)(hout + rbase + cg*16 + kg*4) = o;
      }
    }
    __syncthreads();   // all reads done before next tile's staging overwrites
  }

  #pragma unroll
  for (int cg = 0; cg < 4; ++cg)
    #pragma unroll
    for (int m = 1; m <= 8; m <<= 1)
      #pragma unroll
      for (int t = 0; t < 4; ++t){
        sA[cg][t] += __shfl_xor(sA[cg][t], m, 64);
        qA[cg][t] += __shfl_xor(qA[cg][t], m, 64);
      }
  if (m16 == 0){
    #pragma unroll
    for (int cg = 0; cg < 4; ++cg)
      #pragma unroll
      for (int t = 0; t < 4; ++t){
        atomicAdd(&sacc[cg*16 + kg*4 + t], sA[cg][t]);
        atomicAdd(&sacc[64 + cg*16 + kg*4 + t], qA[cg][t]);
      }
  }
  __syncthreads();
  if (tid < 128) atomicAdd(&acc[(blockIdx.x & 3)*128 + tid], sacc[tid]);
}

// ---------- Layer 1: in-kernel ss0 (4-bank sum) + packed-f16 norm+relu + SWAPPED MFMA f16 ----------
// 512 blocks x 4 row-tiles.
__global__ __launch_bounds__(256) void l1_mfma(const unsigned* __restrict__ hin,
                                               const float* __restrict__ acc0,  // 4 x 128
                                               const float* __restrict__ g,
                                               const float* __restrict__ be,
                                               const float* __restrict__ W,     // (64,64)
                                               const float* __restrict__ bias,  // (64)
                                               unsigned short* __restrict__ hout,
                                               float* __restrict__ acc1){       // 4 x 128
  __shared__ float ssl[128];
  __shared__ float sacc[128];
  const int tid = threadIdx.x;
  if (tid < 128) sacc[tid] = 0.f;
  if (tid < 64){
    float s = 0.f, q = 0.f;
    #pragma unroll
    for (int bnk = 0; bnk < 4; ++bnk){
      s += acc0[bnk*128 + tid];
      q += acc0[bnk*128 + 64 + tid];
    }
    const float invM = 1.f / (float)MROWS;
    const float mean = s * invM;
    const float var  = q * invM - mean*mean;
    const float scale = g[tid] * rsqrtf(var + 1e-5f);
    ssl[2*tid + 0] = scale;
    ssl[2*tid + 1] = be[tid] - mean * scale;
  }
  __syncthreads();

  const int lane = tid & 63, wv = tid >> 6;
  const int m16 = lane & 15, kg = lane >> 4;

  half8 scl8[2], shf8[2];
  #pragma unroll
  for (int s2 = 0; s2 < 2; ++s2)
    #pragma unroll
    for (int i = 0; i < 8; ++i){
      const int c = s2*32 + kg*8 + i;
      scl8[s2][i] = (_Float16)ssl[2*c + 0];
      shf8[s2][i] = (_Float16)ssl[2*c + 1];
    }

  half8  Wf[4][2];
  f32x4  bl4[4];
  for (int cg = 0; cg < 4; ++cg){
    bl4[cg] = *(const f32x4*)(bias + cg*16 + kg*4);
    const int n = cg*16 + m16;
    #pragma unroll
    for (int s2 = 0; s2 < 2; ++s2){
      half8 t;
      #pragma unroll
      for (int i = 0; i < 8; ++i)
        t[i] = (_Float16)W[n*64 + s2*32 + kg*8 + i];
      Wf[cg][s2] = t;
    }
  }

  f32x4 zero4 = {0.f, 0.f, 0.f, 0.f};
  f32x4 sA[4] = {zero4, zero4, zero4, zero4};
  f32x4 qA[4] = {zero4, zero4, zero4, zero4};

  for (int tt = 0; tt < 4; ++tt){
    const int rowbase = (blockIdx.x*4 + tt)*256 + wv*64;
    for (int rt = 0; rt < 4; ++rt){
      const int arow = rowbase + rt*16 + m16;
      const uint4* pr = (const uint4*)hin + (size_t)arow*8;
      uint4 v0 = pr[kg];
      uint4 v1 = pr[4 + kg];
      half8 x0 = norm_frag_h(v0, scl8[0], shf8[0]);
      half8 x1 = norm_frag_h(v1, scl8[1], shf8[1]);
      const size_t rbase = (size_t)arow * 64;
      #pragma unroll
      for (int cg = 0; cg < 4; ++cg){
        f32x4 c = bl4[cg];
        c = __builtin_amdgcn_mfma_f32_16x16x32_f16(Wf[cg][0], x0, c, 0, 0, 0);
        c = __builtin_amdgcn_mfma_f32_16x16x32_f16(Wf[cg][1], x1, c, 0, 0, 0);
        sA[cg] += c; qA[cg] += c*c;
        uint2 o;
        o.x = cvt_pk_f16(c[0], c[1]);
        o.y = cvt_pk_f16(c[2], c[3]);
        *(uint2*)(hout + rbase + cg*16 + kg*4) = o;
      }
    }
  }
  #pragma unroll
  for (int cg = 0; cg < 4; ++cg)
    #pragma unroll
    for (int m = 1; m <= 8; m <<= 1)
      #pragma unroll
      for (int t = 0; t < 4; ++t){
        sA[cg][t] += __shfl_xor(sA[cg][t], m, 64);
        qA[cg][t] += __shfl_xor(qA[cg][t], m, 64);
      }
  if (m16 == 0){
    #pragma unroll
    for (int cg = 0; cg < 4; ++cg)
      #pragma unroll
      for (int t = 0; t < 4; ++t){
        atomicAdd(&sacc[cg*16 + kg*4 + t], sA[cg][t]);
        atomicAdd(&sacc[64 + cg*16 + kg*4 + t], qA[cg][t]);
      }
  }
  __syncthreads();
  if (tid < 128) atomicAdd(&acc1[(blockIdx.x & 3)*128 + tid], sacc[tid]);
}

// ---------- Layer 2 FUSED: in-kernel ss1 (4-bank) + packed-f16 norm + f16 GEMM 64->128 + stats + max/min ----------
// 512 blocks x 4 row-tiles.
__global__ __launch_bounds__(256) void l2_fused(const unsigned* __restrict__ hin,
                                                const float* __restrict__ acc1,  // 4 x 128
                                                const float* __restrict__ g,
                                                const float* __restrict__ be,
                                                const float* __restrict__ W,     // (128,64)
                                                const float* __restrict__ bias,  // (128)
                                                float* __restrict__ maxb,        // (16384,128)
                                                float* __restrict__ minb,        // (16384,128)
                                                float* __restrict__ acc2){       // 4 x 256
  __shared__ float ssl[128];
  __shared__ float sacc[256];
  const int tid = threadIdx.x;
  sacc[tid] = 0.f;
  if (tid < 64){
    float s = 0.f, q = 0.f;
    #pragma unroll
    for (int bnk = 0; bnk < 4; ++bnk){
      s += acc1[bnk*128 + tid];
      q += acc1[bnk*128 + 64 + tid];
    }
    const float invM = 1.f / (float)MROWS;
    const float mean = s * invM;
    const float var  = q * invM - mean*mean;
    const float scale = g[tid] * rsqrtf(var + 1e-5f);
    ssl[2*tid + 0] = scale;
    ssl[2*tid + 1] = be[tid] - mean * scale;
  }
  __syncthreads();

  const int lane = tid & 63, wv = tid >> 6;
  const int m16 = lane & 15, kg = lane >> 4;

  half8 scl8[2], shf8[2];
  #pragma unroll
  for (int s2 = 0; s2 < 2; ++s2)
    #pragma unroll
    for (int i = 0; i < 8; ++i){
      const int c = s2*32 + kg*8 + i;
      scl8[s2][i] = (_Float16)ssl[2*c + 0];
      shf8[s2][i] = (_Float16)ssl[2*c + 1];
    }

  half8 Bf[8][2];
  float bl[8];
  for (int ocb = 0; ocb < 8; ++ocb){
    const int n = ocb*16 + m16;
    bl[ocb] = bias[n];
    #pragma unroll
    for (int s2 = 0; s2 < 2; ++s2){
      half8 t;
      #pragma unroll
      for (int i = 0; i < 8; ++i)
        t[i] = (_Float16)W[n*64 + s2*32 + kg*8 + i];
      Bf[ocb][s2] = t;
    }
  }

  float sA[8], qA[8];
  #pragma unroll
  for (int o = 0; o < 8; ++o){ sA[o] = 0.f; qA[o] = 0.f; }

  for (int tt = 0; tt < 4; ++tt){
    const int rowbase = (blockIdx.x*4 + tt)*256 + wv*64;   // 2 queries per wave
    float mx[2][8], mn[2][8];
    #pragma unroll
    for (int o = 0; o < 8; ++o){
      mx[0][o] = -FLT_MAX_; mx[1][o] = -FLT_MAX_;
      mn[0][o] =  FLT_MAX_; mn[1][o] =  FLT_MAX_;
    }
    #pragma unroll
    for (int rt = 0; rt < 4; ++rt){
      const int qs = rt >> 1;
      const int arow = rowbase + rt*16 + m16;
      const uint4* pr = (const uint4*)hin + (size_t)arow*8;
      uint4 v0 = pr[kg];
      uint4 v1 = pr[4 + kg];
      half8 a0 = norm_frag_h(v0, scl8[0], shf8[0]);
      half8 a1 = norm_frag_h(v1, scl8[1], shf8[1]);
      #pragma unroll
      for (int ocb = 0; ocb < 8; ++ocb){
        f32x4 c = {bl[ocb], bl[ocb], bl[ocb], bl[ocb]};
        c = __builtin_amdgcn_mfma_f32_16x16x32_f16(a0, Bf[ocb][0], c, 0, 0, 0);
        c = __builtin_amdgcn_mfma_f32_16x16x32_f16(a1, Bf[ocb][1], c, 0, 0, 0);
        #pragma unroll
        for (int r = 0; r < 4; ++r){
          const float hv = c[r];
          sA[ocb] += hv; qA[ocb] += hv*hv;
          mx[qs][ocb] = fmaxf(mx[qs][ocb], hv);
          mn[qs][ocb] = fminf(mn[qs][ocb], hv);
        }
      }
    }
    const int qa = rowbase >> 5;
    #pragma unroll
    for (int qs = 0; qs < 2; ++qs)
      #pragma unroll
      for (int ocb = 0; ocb < 8; ++ocb){
        float a = mx[qs][ocb], b = mn[qs][ocb];
        a = fmaxf(a, __shfl_xor(a, 16, 64)); a = fmaxf(a, __shfl_xor(a, 32, 64));
        b = fminf(b, __shfl_xor(b, 16, 64)); b = fminf(b, __shfl_xor(b, 32, 64));
        if (kg == 0){
          maxb[(size_t)(qa + qs)*128 + ocb*16 + m16] = a;
          minb[(size_t)(qa + qs)*128 + ocb*16 + m16] = b;
        }
      }
  }

  #pragma unroll
  for (int ocb = 0; ocb < 8; ++ocb){
    float s = sA[ocb], q = qA[ocb];
    s += __shfl_xor(s, 16, 64); s += __shfl_xor(s, 32, 64);
    q += __shfl_xor(q, 16, 64); q += __shfl_xor(q, 32, 64);
    if (kg == 0){
      atomicAdd(&sacc[ocb*16 + m16], s);
      atomicAdd(&sacc[128 + ocb*16 + m16], q);
    }
  }
  __syncthreads();
  atomicAdd(&acc2[(blockIdx.x & 3)*256 + tid], sacc[tid]);
}

// ---------- Final: in-kernel ss2 (4-bank); out = relu(scale*(scale>=0?max:min)+shift) ----------
__global__ __launch_bounds__(256) void final_kernel(const float* __restrict__ xyz,
                                                    const float* __restrict__ maxb,
                                                    const float* __restrict__ minb,
                                                    const float* __restrict__ acc2, // 4 x 256
                                                    const float* __restrict__ g,
                                                    const float* __restrict__ be,
                                                    float* __restrict__ out){
  __shared__ float ssl[256];
  const int tid = threadIdx.x;
  if (tid < 128){
    float s = 0.f, q = 0.f;
    #pragma unroll
    for (int bnk = 0; bnk < 4; ++bnk){
      s += acc2[bnk*256 + tid];
      q += acc2[bnk*256 + 128 + tid];
    }
    const float invM = 1.f / (float)MROWS;
    const float mean = s * invM;
    const float var  = q * invM - mean*mean;
    const float scale = g[tid] * rsqrtf(var + 1e-5f);
    ssl[2*tid + 0] = scale;
    ssl[2*tid + 1] = be[tid] - mean * scale;
  }
  __syncthreads();

  const int q = blockIdx.x * 4 + (tid >> 6);
  const int p = tid & 63;
  const float sc0 = ssl[4*p + 0], sh0 = ssl[4*p + 1];
  const float sc1 = ssl[4*p + 2], sh1 = ssl[4*p + 3];
  const float2 mxv = ((const float2*)(maxb + (size_t)q*128))[p];
  const float2 mnv = ((const float2*)(minb + (size_t)q*128))[p];
  const float h0v = (sc0 >= 0.f) ? mxv.x : mnv.x;
  const float h1v = (sc1 >= 0.f) ? mxv.y : mnv.y;
  float2 r;
  r.x = fmaxf(fmaf(sc0, h0v, sh0), 0.f);
  r.y = fmaxf(fmaf(sc1, h1v, sh1), 0.f);
  ((float2*)(out + (size_t)NB*NQ*3))[(size_t)q*64 + p] = r;
  if (p < 3){
    const int b_ = q >> 10, s = q & 1023;
    out[(size_t)q*3 + p] = xyz[((size_t)b_ * NPTS + s)*3 + p];
  }
}

// ---------- host ----------
extern "C" void kernel_launch(void* const* d_in, const int* in_sizes, int n_in,
                              void* d_out, int out_size, void* d_ws, size_t ws_size,
                              hipStream_t stream){
  (void)in_sizes; (void)n_in; (void)out_size; (void)ws_size;
  const float* xyz = (const float*)d_in[0];
  const float* pts = (const float*)d_in[1];
  const float* W0  = (const float*)d_in[2];
  const float* b0  = (const float*)d_in[3];
  const float* g0  = (const float*)d_in[4];
  const float* be0 = (const float*)d_in[5];
  const float* W1  = (const float*)d_in[6];
  const float* b1  = (const float*)d_in[7];
  const float* g1  = (const float*)d_in[8];
  const float* be1 = (const float*)d_in[9];
  const float* W2  = (const float*)d_in[10];
  const float* b2  = (const float*)d_in[11];
  const float* g2  = (const float*)d_in[12];
  const float* be2 = (const float*)d_in[13];

  // workspace: idx 2MB | acc 2048f (acc0 4x128 | acc1 4x128 | acc2 4x256) | h0 64MB | h1 64MB
  char* ws = (char*)d_ws;
  int*   idx = (int*)ws;
  float* acc = (float*)(ws + 2097152);
  unsigned* h0 = (unsigned*)(ws + 2097152 + 8192);
  unsigned* h1 = (unsigned*)(ws + 2097152 + 8192 + 67108864);
  float* maxb = (float*)h0;                    // reuses h0 (dead after l1)
  float* minb = maxb + (size_t)16384*128;
  float* out = (float*)d_out;

  float* acc0 = acc, *acc1 = acc + 512, *acc2 = acc + 1024;

  topk_kernel<<<512, 1024, 0, stream>>>(xyz, idx, acc);
  l0_mfma<<<512, 256, 0, stream>>>(xyz, pts, idx, W0, b0, (unsigned short*)h0, acc0);
  l1_mfma<<<512, 256, 0, stream>>>(h0, acc0, g0, be0, W1, b1, (unsigned short*)h1, acc1);
  l2_fused<<<512, 256, 0, stream>>>(h1, acc1, g1, be1, W2, b2, maxb, minb, acc2);
  final_kernel<<<4096, 256, 0, stream>>>(xyz, maxb, minb, acc2, g2, be2, out);
}

// Round 26
// 192.322 us; speedup vs baseline: 1.1306x; 1.0087x over previous
//
#include <hip/hip_runtime.h>

#define NPTS 4096
#define NQ   1024     // S
#define NB   16       // B
#define KNN  32
#define MROWS 524288  // B*S*K
#define FLT_MAX_ 3.402823466e+38f

typedef __attribute__((ext_vector_type(8))) _Float16 half8;
typedef __attribute__((ext_vector_type(4))) float f32x4;

// ---------- f16 helpers ----------
__device__ __forceinline__ unsigned cvt_pk_f16(float lo, float hi){
  auto v = __builtin_amdgcn_cvt_pkrtz(lo, hi);
  union { decltype(v) h; unsigned u; } cv; cv.h = v;
  return cv.u;
}

// normalize+relu 8 f16 channels via native packed-half fma/max
__device__ __forceinline__ half8 norm_frag_h(uint4 v, half8 sc, half8 sh){
  union { uint4 u4; half8 h8; } cv;
  cv.u4 = v;
  half8 r = cv.h8 * sc + sh;
  const half8 z8 = (half8)(_Float16)0.f;
  return __builtin_elementwise_max(r, z8);
}

// ---------- topk helpers (R16-proven) ----------
// PINNED distance: every add lives inside an explicit fmaf -> no contraction
// freedom -> bit-identical value at every call site (count/emit consistency).
__device__ __forceinline__ float distf(float4 pv, float qx, float qy, float qz, float s2){
  const float dot = fmaf(qx, pv.x, fmaf(qy, pv.y, qz * pv.z));
  return fmaf(-2.f, dot, s2 + pv.w);
}

// payload-free f32 top-7 insert (all levels read OLD values; 1-deep, full-rate)
__device__ __forceinline__ void ins7f(float d, float& c0, float& c1, float& c2,
                                      float& c3, float& c4, float& c5, float& c6){
  const float n0 = fminf(d, c0);
  const float n1 = __builtin_amdgcn_fmed3f(d, c0, c1);
  const float n2 = __builtin_amdgcn_fmed3f(d, c1, c2);
  const float n3 = __builtin_amdgcn_fmed3f(d, c2, c3);
  const float n4 = __builtin_amdgcn_fmed3f(d, c3, c4);
  const float n5 = __builtin_amdgcn_fmed3f(d, c4, c5);
  const float n6 = __builtin_amdgcn_fmed3f(d, c5, c6);
  c0 = n0; c1 = n1; c2 = n2; c3 = n3; c4 = n4; c5 = n5; c6 = n6;
}

__device__ __forceinline__ void ins5d(double pd, double& c0, double& c1, double& c2,
                                      double& c3, double& c4){
  const double t4 = fmin(c4, pd);
  const double n3 = fmin(c3, t4), x4 = fmax(c3, t4);
  const double n2 = fmin(c2, n3), x3 = fmax(c2, n3);
  const double n1 = fmin(c1, n2), x2 = fmax(c1, n2);
  const double n0 = fmin(c0, n1), x1 = fmax(c0, n1);
  c0 = n0; c1 = x1; c2 = x2; c3 = x3; c4 = x4;
}

__device__ __forceinline__ void scan5d(const float4* pbuf, int lane,
                                       float qx, float qy, float qz, float src2,
                                       unsigned long long skip,
                                       double& c0, double& c1, double& c2, double& c3, double& c4){
  for (int e = 0; e < 64; ++e){
    if ((skip >> e) & 1ull) continue;
    const int j = (e << 6) | lane;
    const float d = distf(pbuf[j], qx, qy, qz, src2);
    const unsigned long long uu =
        (unsigned long long)__double_as_longlong((double)d) | (unsigned)j;
    ins5d(__longlong_as_double((long long)uu), c0, c1, c2, c3, c4);
  }
}

// COLD exact fallback — noinline keeps the hot loop small. All selection state
// is internal (by-value args in, global writes out) -> no R6 spill trap.
__device__ __noinline__ void extract_exact(const float4* pbuf, int lane,
                                           float qx, float qy, float qz, float src2,
                                           int qidx, int* idx_out){
  const double DINF = __builtin_inf();
  double c0 = DINF, c1 = DINF, c2 = DINF, c3 = DINF, c4 = DINF;
  scan5d(pbuf, lane, qx, qy, qz, src2, 0ull, c0, c1, c2, c3, c4);
  unsigned long long skip = 0ull;
  int nc = 5;
  int win = 0;
  #pragma unroll 1
  for (int it = 0; it < KNN; ++it){
    double w = c0;
    #pragma unroll
    for (int m = 32; m >= 1; m >>= 1)
      w = fmin(w, __shfl_xor(w, m, 64));
    if (lane == it) win = (int)((unsigned)__double_as_longlong(w) & 0xFFFu);
    if (c0 == w){
      const unsigned lo = (unsigned)__double_as_longlong(c0);
      skip |= 1ull << ((lo >> 6) & 63u);
      c0 = c1; c1 = c2; c2 = c3; c3 = c4; c4 = DINF;
      if (--nc == 0){
        c0 = c1 = c2 = c3 = c4 = DINF;
        scan5d(pbuf, lane, qx, qy, qz, src2, skip, c0, c1, c2, c3, c4);
        nc = 5;
      }
    }
  }
  if (lane < KNN) idx_out[qidx * KNN + lane] = win;
}

// COLD single-query emit (only when exactly one query is emit-eligible)
__device__ __noinline__ int emit32(const float4* pbuf, int lane,
                                   float qx, float qy, float qz, float src2,
                                   float T, int* outq){
  int base = 0;
  const unsigned long long below = (1ull << lane) - 1ull;
  for (int e = 0; e < 64; ++e){
    const int j = (e << 6) | lane;
    const float d = distf(pbuf[j], qx, qy, qz, src2);
    const bool hit = d < T;
    const unsigned long long m = __ballot(hit);
    if (hit){
      const int slot = base + __popcll(m & below);
      if (slot < KNN) outq[slot] = j;
    }
    base += __popcll(m);
  }
  return base;
}

// HOT dual-query emit: ONE LDS read per point serves both queries
__device__ __forceinline__ int2 emit32_dual(const float4* pbuf, int lane,
                                            float axq, float ayq, float azq, float src2A,
                                            float bxq, float byq, float bzq, float src2B,
                                            float TA, float TB, int* outA, int* outB){
  int baseA = 0, baseB = 0;
  const unsigned long long below = (1ull << lane) - 1ull;
  for (int e = 0; e < 64; ++e){
    const int j = (e << 6) | lane;
    const float4 pv = pbuf[j];
    const float dA = distf(pv, axq, ayq, azq, src2A);
    const float dB = distf(pv, bxq, byq, bzq, src2B);
    const bool hA = dA < TA;
    const bool hB = dB < TB;
    const unsigned long long mA = __ballot(hA);
    const unsigned long long mB = __ballot(hB);
    if (hA){
      const int slot = baseA + __popcll(mA & below);
      if (slot < KNN) outA[slot] = j;
    }
    if (hB){
      const int slot = baseB + __popcll(mB & below);
      if (slot < KNN) outB[slot] = j;
    }
    baseA += __popcll(mA);
    baseB += __popcll(mB);
  }
  return make_int2(baseA, baseB);
}

// wave-wide f32 min/max
__device__ __forceinline__ float wave_minf(float v){
  #pragma unroll
  for (int m = 32; m >= 1; m >>= 1) v = fminf(v, __shfl_xor(v, m, 64));
  return v;
}
__device__ __forceinline__ float wave_maxf(float v){
  #pragma unroll
  for (int m = 32; m >= 1; m >>= 1) v = fmaxf(v, __shfl_xor(v, m, 64));
  return v;
}

// ---------- Kernel 1: top-K=32 NN via f32 top-7 + f32 threshold bisection ----------
// Top-7 cache cuts the exact-fallback (straggler) rate another ~10x vs top-6.
__global__ __launch_bounds__(1024) void topk_kernel(const float* __restrict__ xyz,
                                                    int* __restrict__ idx_out,
                                                    float* __restrict__ statsacc){
  __shared__ float4 pbuf[NPTS];          // 64 KB: x, y, z, |p|^2
  const int tid = threadIdx.x;
  if (blockIdx.x == 0){
    statsacc[tid] = 0.f;
    statsacc[tid + 1024] = 0.f;
  }

  const int b = blockIdx.x >> 5;         // 32 blocks per batch, 32 queries/block
  const float* xb = xyz + (size_t)b * NPTS * 3;
  for (int p = tid; p < NPTS; p += 1024){
    const float x = xb[3*p + 0], y = xb[3*p + 1], z = xb[3*p + 2];
    pbuf[p] = make_float4(x, y, z, fmaf(x, x, fmaf(y, y, z*z)));
  }
  __syncthreads();

  const int wv   = tid >> 6;
  const int lane = tid & 63;
  const int qA   = blockIdx.x * 32 + wv*2;
  const int qB   = qA + 1;
  const int sA_  = qA & (NQ - 1);
  const int sB_  = qB & (NQ - 1);

  const float4 qpA = pbuf[sA_];
  const float4 qpB = pbuf[sB_];
  const float axq = qpA.x, ayq = qpA.y, azq = qpA.z, src2A = qpA.w;
  const float bxq = qpB.x, byq = qpB.y, bzq = qpB.z, src2B = qpB.w;

  float a0 = FLT_MAX_, a1 = FLT_MAX_, a2 = FLT_MAX_, a3 = FLT_MAX_,
        a4 = FLT_MAX_, a5 = FLT_MAX_, a6 = FLT_MAX_;
  float b0 = FLT_MAX_, b1 = FLT_MAX_, b2 = FLT_MAX_, b3 = FLT_MAX_,
        b4 = FLT_MAX_, b5 = FLT_MAX_, b6 = FLT_MAX_;
  for (int e = 0; e < 64; ++e){
    const int j = (e << 6) | lane;
    const float4 pv = pbuf[j];
    const float dA = distf(pv, axq, ayq, azq, src2A);
    const float dB = distf(pv, bxq, byq, bzq, src2B);
    ins7f(dA, a0, a1, a2, a3, a4, a5, a6);
    ins7f(dB, b0, b1, b2, b3, b4, b5, b6);
  }

  // data-driven bisection bounds: cnt(lo)=0 < 32 <= cnt(hi)=448 on caches.
  // Any T in (k32,k33] yields the SAME emitted set -> speed-only change.
  float loA = wave_minf(a0), loB = wave_minf(b0);
  float hiA = wave_maxf(a6), hiB = wave_maxf(b6);
  hiA = fmaf(fabsf(hiA), 1e-6f, hiA) + 1e-30f;
  hiB = fmaf(fabsf(hiB), 1e-6f, hiB) + 1e-30f;
  float TA = 0.f, TB = 0.f;
  bool doneA = false, doneB = false;
  #pragma unroll 1
  for (int bi = 0; bi < 32 && !(doneA && doneB); ++bi){
    if (!doneA){
      const float g = 0.5f*(loA + hiA);
      const int cnt = __popcll(__ballot(a0 < g)) + __popcll(__ballot(a1 < g))
                    + __popcll(__ballot(a2 < g)) + __popcll(__ballot(a3 < g))
                    + __popcll(__ballot(a4 < g)) + __popcll(__ballot(a5 < g))
                    + __popcll(__ballot(a6 < g));
      if (cnt >= KNN){ hiA = g; if (cnt == KNN){ TA = g; doneA = true; } }
      else loA = g;
    }
    if (!doneB){
      const float g = 0.5f*(loB + hiB);
      const int cnt = __popcll(__ballot(b0 < g)) + __popcll(__ballot(b1 < g))
                    + __popcll(__ballot(b2 < g)) + __popcll(__ballot(b3 < g))
                    + __popcll(__ballot(b4 < g)) + __popcll(__ballot(b5 < g))
                    + __popcll(__ballot(b6 < g));
      if (cnt >= KNN){ hiB = g; if (cnt == KNN){ TB = g; doneB = true; } }
      else loB = g;
    }
  }

  // validity: no lane's whole cache below T (else an evicted 8th could be < T)
  bool okA = doneA && !__any(a6 < TA);
  bool okB = doneB && !__any(b6 < TB);
  if (okA && okB){
    const int2 c = emit32_dual(pbuf, lane, axq, ayq, azq, src2A,
                               bxq, byq, bzq, src2B, TA, TB,
                               idx_out + qA * KNN, idx_out + qB * KNN);
    okA = (c.x == KNN);
    okB = (c.y == KNN);
  } else {
    if (okA)
      okA = (emit32(pbuf, lane, axq, ayq, azq, src2A, TA, idx_out + qA * KNN) == KNN);
    if (okB)
      okB = (emit32(pbuf, lane, bxq, byq, bzq, src2B, TB, idx_out + qB * KNN) == KNN);
  }
  if (!okA) extract_exact(pbuf, lane, axq, ayq, azq, src2A, qA, idx_out);
  if (!okB) extract_exact(pbuf, lane, bxq, byq, bzq, src2B, qB, idx_out);
}

// ---------- Layer 0: gather + concat + SWAPPED MFMA f16 GEMM, 512 blocks x 4 tiles ----------
__global__ __launch_bounds__(256) void l0_mfma(const float* __restrict__ xyz,
                                               const float* __restrict__ pts,
                                               const int*   __restrict__ idxbuf,
                                               const float* __restrict__ W,     // (64,67)
                                               const float* __restrict__ bias,  // (64)
                                               unsigned short* __restrict__ hout,
                                               float* __restrict__ acc){        // 4 x 128
  __shared__ short lds[256*104];
  __shared__ float sacc[128];
  const int tid = threadIdx.x;
  if (tid < 128) sacc[tid] = 0.f;
  const int lane = tid & 63, wv = tid >> 6;
  const int m16 = lane & 15, kg = lane >> 4;

  half8  Wf[4][3];
  f32x4  bl4[4];
  for (int cg = 0; cg < 4; ++cg){
    bl4[cg] = *(const f32x4*)(bias + cg*16 + kg*4);
    const int n = cg*16 + m16;
    for (int ks = 0; ks < 3; ++ks){
      half8 t;
      #pragma unroll
      for (int i = 0; i < 8; ++i){
        const int k = ks*32 + kg*8 + i;
        float wv_ = 0.f;
        if (k < 64) wv_ = W[n*67 + 3 + k];
        else if (k < 67) wv_ = W[n*67 + (k - 64)];
        t[i] = (_Float16)wv_;
      }
      Wf[cg][ks] = t;
    }
  }

  f32x4 zero4 = {0.f, 0.f, 0.f, 0.f};
  f32x4 sA[4] = {zero4, zero4, zero4, zero4};
  f32x4 qA[4] = {zero4, zero4, zero4, zero4};

  for (int tt = 0; tt < 4; ++tt){
    const int tilebase = (blockIdx.x*4 + tt)*256;
    {
      const int row = tilebase + tid;
      const int rowq = row >> 5;
      const int b = rowq >> 10, s = rowq & 1023;
      const int j = idxbuf[row];
      const float4* p4 = (const float4*)(pts + ((size_t)b*NPTS + j)*64);
      short* myrow = lds + tid*104;
      #pragma unroll
      for (int u = 0; u < 8; ++u){
        float4 x = p4[2*u], y = p4[2*u+1];
        uint4 o;
        o.x = cvt_pk_f16(x.x, x.y);
        o.y = cvt_pk_f16(x.z, x.w);
        o.z = cvt_pk_f16(y.x, y.y);
        o.w = cvt_pk_f16(y.z, y.w);
        *(uint4*)(myrow + u*8) = o;
      }
      const float* pj = xyz + ((size_t)b*NPTS + j)*3;
      const float* ps = xyz + ((size_t)b*NPTS + s)*3;
      uint4 z;
      z.x = cvt_pk_f16(pj[0]-ps[0], pj[1]-ps[1]);
      z.y = cvt_pk_f16(pj[2]-ps[2], 0.f);
      z.z = 0u; z.w = 0u;
      *(uint4*)(myrow + 64) = z;
      uint4 zz; zz.x = zz.y = zz.z = zz.w = 0u;
      *(uint4*)(myrow + 72) = zz;
      *(uint4*)(myrow + 80) = zz;
      *(uint4*)(myrow + 88) = zz;
    }
    __syncthreads();

    const int rowbase = tilebase + wv*64;
    for (int rt = 0; rt < 4; ++rt){
      const short* ar = lds + (wv*64 + rt*16 + m16)*104;
      half8 x0 = *(const half8*)(ar + kg*8);
      half8 x1 = *(const half8*)(ar + 32 + kg*8);
      half8 x2 = *(const half8*)(ar + 64 + kg*8);
      const size_t rbase = (size_t)(rowbase + rt*16 + m16) * 64;
      #pragma unroll
      for (int cg = 0; cg < 4; ++cg){
        f32x4 c = bl4[cg];
        c = __builtin_amdgcn_mfma_f32_16x16x32_f16(Wf[cg][0], x0, c, 0, 0, 0);
        c = __builtin_amdgcn_mfma_f32_16x16x32_f16(Wf[cg][1], x1, c, 0, 0, 0);
        c = __builtin_amdgcn_mfma_f32_16x16x32_f16(Wf[cg][2], x2, c, 0, 0, 0);
        sA[cg] += c; qA[cg] += c*c;
        uint2 o;
        o.x = cvt_pk_f16(c[0], c[1]);
        o.y = cvt_pk_f16(c[2], c[3]);
        *(uint2*)(hout + rbase + cg*16 + kg*4) = o;
      }
    }
    __syncthreads();   // all reads done before next tile's staging overwrites
  }

  #pragma unroll
  for (int cg = 0; cg < 4; ++cg)
    #pragma unroll
    for (int m = 1; m <= 8; m <<= 1)
      #pragma unroll
      for (int t = 0; t < 4; ++t){
        sA[cg][t] += __shfl_xor(sA[cg][t], m, 64);
        qA[cg][t] += __shfl_xor(qA[cg][t], m, 64);
      }
  if (m16 == 0){
    #pragma unroll
    for (int cg = 0; cg < 4; ++cg)
      #pragma unroll
      for (int t = 0; t < 4; ++t){
        atomicAdd(&sacc[cg*16 + kg*4 + t], sA[cg][t]);
        atomicAdd(&sacc[64 + cg*16 + kg*4 + t], qA[cg][t]);
      }
  }
  __syncthreads();
  if (tid < 128) atomicAdd(&acc[(blockIdx.x & 3)*128 + tid], sacc[tid]);
}

// ---------- Layer 1: in-kernel ss0 (4-bank sum) + packed-f16 norm+relu + SWAPPED MFMA f16 ----------
// 512 blocks x 4 row-tiles.
__global__ __launch_bounds__(256) void l1_mfma(const unsigned* __restrict__ hin,
                                               const float* __restrict__ acc0,  // 4 x 128
                                               const float* __restrict__ g,
                                               const float* __restrict__ be,
                                               const float* __restrict__ W,     // (64,64)
                                               const float* __restrict__ bias,  // (64)
                                               unsigned short* __restrict__ hout,
                                               float* __restrict__ acc1){       // 4 x 128
  __shared__ float ssl[128];
  __shared__ float sacc[128];
  const int tid = threadIdx.x;
  if (tid < 128) sacc[tid] = 0.f;
  if (tid < 64){
    float s = 0.f, q = 0.f;
    #pragma unroll
    for (int bnk = 0; bnk < 4; ++bnk){
      s += acc0[bnk*128 + tid];
      q += acc0[bnk*128 + 64 + tid];
    }
    const float invM = 1.f / (float)MROWS;
    const float mean = s * invM;
    const float var  = q * invM - mean*mean;
    const float scale = g[tid] * rsqrtf(var + 1e-5f);
    ssl[2*tid + 0] = scale;
    ssl[2*tid + 1] = be[tid] - mean * scale;
  }
  __syncthreads();

  const int lane = tid & 63, wv = tid >> 6;
  const int m16 = lane & 15, kg = lane >> 4;

  half8 scl8[2], shf8[2];
  #pragma unroll
  for (int s2 = 0; s2 < 2; ++s2)
    #pragma unroll
    for (int i = 0; i < 8; ++i){
      const int c = s2*32 + kg*8 + i;
      scl8[s2][i] = (_Float16)ssl[2*c + 0];
      shf8[s2][i] = (_Float16)ssl[2*c + 1];
    }

  half8  Wf[4][2];
  f32x4  bl4[4];
  for (int cg = 0; cg < 4; ++cg){
    bl4[cg] = *(const f32x4*)(bias + cg*16 + kg*4);
    const int n = cg*16 + m16;
    #pragma unroll
    for (int s2 = 0; s2 < 2; ++s2){
      half8 t;
      #pragma unroll
      for (int i = 0; i < 8; ++i)
        t[i] = (_Float16)W[n*64 + s2*32 + kg*8 + i];
      Wf[cg][s2] = t;
    }
  }

  f32x4 zero4 = {0.f, 0.f, 0.f, 0.f};
  f32x4 sA[4] = {zero4, zero4, zero4, zero4};
  f32x4 qA[4] = {zero4, zero4, zero4, zero4};

  for (int tt = 0; tt < 4; ++tt){
    const int rowbase = (blockIdx.x*4 + tt)*256 + wv*64;
    for (int rt = 0; rt < 4; ++rt){
      const int arow = rowbase + rt*16 + m16;
      const uint4* pr = (const uint4*)hin + (size_t)arow*8;
      uint4 v0 = pr[kg];
      uint4 v1 = pr[4 + kg];
      half8 x0 = norm_frag_h(v0, scl8[0], shf8[0]);
      half8 x1 = norm_frag_h(v1, scl8[1], shf8[1]);
      const size_t rbase = (size_t)arow * 64;
      #pragma unroll
      for (int cg = 0; cg < 4; ++cg){
        f32x4 c = bl4[cg];
        c = __builtin_amdgcn_mfma_f32_16x16x32_f16(Wf[cg][0], x0, c, 0, 0, 0);
        c = __builtin_amdgcn_mfma_f32_16x16x32_f16(Wf[cg][1], x1, c, 0, 0, 0);
        sA[cg] += c; qA[cg] += c*c;
        uint2 o;
        o.x = cvt_pk_f16(c[0], c[1]);
        o.y = cvt_pk_f16(c[2], c[3]);
        *(uint2*)(hout + rbase + cg*16 + kg*4) = o;
      }
    }
  }
  #pragma unroll
  for (int cg = 0; cg < 4; ++cg)
    #pragma unroll
    for (int m = 1; m <= 8; m <<= 1)
      #pragma unroll
      for (int t = 0; t < 4; ++t){
        sA[cg][t] += __shfl_xor(sA[cg][t], m, 64);
        qA[cg][t] += __shfl_xor(qA[cg][t], m, 64);
      }
  if (m16 == 0){
    #pragma unroll
    for (int cg = 0; cg < 4; ++cg)
      #pragma unroll
      for (int t = 0; t < 4; ++t){
        atomicAdd(&sacc[cg*16 + kg*4 + t], sA[cg][t]);
        atomicAdd(&sacc[64 + cg*16 + kg*4 + t], qA[cg][t]);
      }
  }
  __syncthreads();
  if (tid < 128) atomicAdd(&acc1[(blockIdx.x & 3)*128 + tid], sacc[tid]);
}

// ---------- Layer 2 FUSED: in-kernel ss1 (4-bank) + packed-f16 norm + f16 GEMM 64->128 + stats + max/min ----------
// 512 blocks x 4 row-tiles.
__global__ __launch_bounds__(256) void l2_fused(const unsigned* __restrict__ hin,
                                                const float* __restrict__ acc1,  // 4 x 128
                                                const float* __restrict__ g,
                                                const float* __restrict__ be,
                                                const float* __restrict__ W,     // (128,64)
                                                const float* __restrict__ bias,  // (128)
                                                float* __restrict__ maxb,        // (16384,128)
                                                float* __restrict__ minb,        // (16384,128)
                                                float* __restrict__ acc2){       // 4 x 256
  __shared__ float ssl[128];
  __shared__ float sacc[256];
  const int tid = threadIdx.x;
  sacc[tid] = 0.f;
  if (tid < 64){
    float s = 0.f, q = 0.f;
    #pragma unroll
    for (int bnk = 0; bnk < 4; ++bnk){
      s += acc1[bnk*128 + tid];
      q += acc1[bnk*128 + 64 + tid];
    }
    const float invM = 1.f / (float)MROWS;
    const float mean = s * invM;
    const float var  = q * invM - mean*mean;
    const float scale = g[tid] * rsqrtf(var + 1e-5f);
    ssl[2*tid + 0] = scale;
    ssl[2*tid + 1] = be[tid] - mean * scale;
  }
  __syncthreads();

  const int lane = tid & 63, wv = tid >> 6;
  const int m16 = lane & 15, kg = lane >> 4;

  half8 scl8[2], shf8[2];
  #pragma unroll
  for (int s2 = 0; s2 < 2; ++s2)
    #pragma unroll
    for (int i = 0; i < 8; ++i){
      const int c = s2*32 + kg*8 + i;
      scl8[s2][i] = (_Float16)ssl[2*c + 0];
      shf8[s2][i] = (_Float16)ssl[2*c + 1];
    }

  half8 Bf[8][2];
  float bl[8];
  for (int ocb = 0; ocb < 8; ++ocb){
    const int n = ocb*16 + m16;
    bl[ocb] = bias[n];
    #pragma unroll
    for (int s2 = 0; s2 < 2; ++s2){
      half8 t;
      #pragma unroll
      for (int i = 0; i < 8; ++i)
        t[i] = (_Float16)W[n*64 + s2*32 + kg*8 + i];
      Bf[ocb][s2] = t;
    }
  }

  float sA[8], qA[8];
  #pragma unroll
  for (int o = 0; o < 8; ++o){ sA[o] = 0.f; qA[o] = 0.f; }

  for (int tt = 0; tt < 4; ++tt){
    const int rowbase = (blockIdx.x*4 + tt)*256 + wv*64;   // 2 queries per wave
    float mx[2][8], mn[2][8];
    #pragma unroll
    for (int o = 0; o < 8; ++o){
      mx[0][o] = -FLT_MAX_; mx[1][o] = -FLT_MAX_;
      mn[0][o] =  FLT_MAX_; mn[1][o] =  FLT_MAX_;
    }
    #pragma unroll
    for (int rt = 0; rt < 4; ++rt){
      const int qs = rt >> 1;
      const int arow = rowbase + rt*16 + m16;
      const uint4* pr = (const uint4*)hin + (size_t)arow*8;
      uint4 v0 = pr[kg];
      uint4 v1 = pr[4 + kg];
      half8 a0 = norm_frag_h(v0, scl8[0], shf8[0]);
      half8 a1 = norm_frag_h(v1, scl8[1], shf8[1]);
      #pragma unroll
      for (int ocb = 0; ocb < 8; ++ocb){
        f32x4 c = {bl[ocb], bl[ocb], bl[ocb], bl[ocb]};
        c = __builtin_amdgcn_mfma_f32_16x16x32_f16(a0, Bf[ocb][0], c, 0, 0, 0);
        c = __builtin_amdgcn_mfma_f32_16x16x32_f16(a1, Bf[ocb][1], c, 0, 0, 0);
        #pragma unroll
        for (int r = 0; r < 4; ++r){
          const float hv = c[r];
          sA[ocb] += hv; qA[ocb] += hv*hv;
          mx[qs][ocb] = fmaxf(mx[qs][ocb], hv);
          mn[qs][ocb] = fminf(mn[qs][ocb], hv);
        }
      }
    }
    const int qa = rowbase >> 5;
    #pragma unroll
    for (int qs = 0; qs < 2; ++qs)
      #pragma unroll
      for (int ocb = 0; ocb < 8; ++ocb){
        float a = mx[qs][ocb], b = mn[qs][ocb];
        a = fmaxf(a, __shfl_xor(a, 16, 64)); a = fmaxf(a, __shfl_xor(a, 32, 64));
        b = fminf(b, __shfl_xor(b, 16, 64)); b = fminf(b, __shfl_xor(b, 32, 64));
        if (kg == 0){
          maxb[(size_t)(qa + qs)*128 + ocb*16 + m16] = a;
          minb[(size_t)(qa + qs)*128 + ocb*16 + m16] = b;
        }
      }
  }

  #pragma unroll
  for (int ocb = 0; ocb < 8; ++ocb){
    float s = sA[ocb], q = qA[ocb];
    s += __shfl_xor(s, 16, 64); s += __shfl_xor(s, 32, 64);
    q += __shfl_xor(q, 16, 64); q += __shfl_xor(q, 32, 64);
    if (kg == 0){
      atomicAdd(&sacc[ocb*16 + m16], s);
      atomicAdd(&sacc[128 + ocb*16 + m16], q);
    }
  }
  __syncthreads();
  atomicAdd(&acc2[(blockIdx.x & 3)*256 + tid], sacc[tid]);
}

// ---------- Final: in-kernel ss2 (4-bank); out = relu(scale*(scale>=0?max:min)+shift) ----------
__global__ __launch_bounds__(256) void final_kernel(const float* __restrict__ xyz,
                                                    const float* __restrict__ maxb,
                                                    const float* __restrict__ minb,
                                                    const float* __restrict__ acc2, // 4 x 256
                                                    const float* __restrict__ g,
                                                    const float* __restrict__ be,
                                                    float* __restrict__ out){
  __shared__ float ssl[256];
  const int tid = threadIdx.x;
  if (tid < 128){
    float s = 0.f, q = 0.f;
    #pragma unroll
    for (int bnk = 0; bnk < 4; ++bnk){
      s += acc2[bnk*256 + tid];
      q += acc2[bnk*256 + 128 + tid];
    }
    const float invM = 1.f / (float)MROWS;
    const float mean = s * invM;
    const float var  = q * invM - mean*mean;
    const float scale = g[tid] * rsqrtf(var + 1e-5f);
    ssl[2*tid + 0] = scale;
    ssl[2*tid + 1] = be[tid] - mean * scale;
  }
  __syncthreads();

  const int q = blockIdx.x * 4 + (tid >> 6);
  const int p = tid & 63;
  const float sc0 = ssl[4*p + 0], sh0 = ssl[4*p + 1];
  const float sc1 = ssl[4*p + 2], sh1 = ssl[4*p + 3];
  const float2 mxv = ((const float2*)(maxb + (size_t)q*128))[p];
  const float2 mnv = ((const float2*)(minb + (size_t)q*128))[p];
  const float h0v = (sc0 >= 0.f) ? mxv.x : mnv.x;
  const float h1v = (sc1 >= 0.f) ? mxv.y : mnv.y;
  float2 r;
  r.x = fmaxf(fmaf(sc0, h0v, sh0), 0.f);
  r.y = fmaxf(fmaf(sc1, h1v, sh1), 0.f);
  ((float2*)(out + (size_t)NB*NQ*3))[(size_t)q*64 + p] = r;
  if (p < 3){
    const int b_ = q >> 10, s = q & 1023;
    out[(size_t)q*3 + p] = xyz[((size_t)b_ * NPTS + s)*3 + p];
  }
}

// ---------- host ----------
extern "C" void kernel_launch(void* const* d_in, const int* in_sizes, int n_in,
                              void* d_out, int out_size, void* d_ws, size_t ws_size,
                              hipStream_t stream){
  (void)in_sizes; (void)n_in; (void)out_size; (void)ws_size;
  const float* xyz = (const float*)d_in[0];
  const float* pts = (const float*)d_in[1];
  const float* W0  = (const float*)d_in[2];
  const float* b0  = (const float*)d_in[3];
  const float* g0  = (const float*)d_in[4];
  const float* be0 = (const float*)d_in[5];
  const float* W1  = (const float*)d_in[6];
  const float* b1  = (const float*)d_in[7];
  const float* g1  = (const float*)d_in[8];
  const float* be1 = (const float*)d_in[9];
  const float* W2  = (const float*)d_in[10];
  const float* b2  = (const float*)d_in[11];
  const float* g2  = (const float*)d_in[12];
  const float* be2 = (const float*)d_in[13];

  // workspace: idx 2MB | acc 2048f (acc0 4x128 | acc1 4x128 | acc2 4x256) | h0 64MB | h1 64MB
  char* ws = (char*)d_ws;
  int*   idx = (int*)ws;
  float* acc = (float*)(ws + 2097152);
  unsigned* h0 = (unsigned*)(ws + 2097152 + 8192);
  unsigned* h1 = (unsigned*)(ws + 2097152 + 8192 + 67108864);
  float* maxb = (float*)h0;                    // reuses h0 (dead after l1)
  float* minb = maxb + (size_t)16384*128;
  float* out = (float*)d_out;

  float* acc0 = acc, *acc1 = acc + 512, *acc2 = acc + 1024;

  topk_kernel<<<512, 1024, 0, stream>>>(xyz, idx, acc);
  l0_mfma<<<512, 256, 0, stream>>>(xyz, pts, idx, W0, b0, (unsigned short*)h0, acc0);
  l1_mfma<<<512, 256, 0, stream>>>(h0, acc0, g0, be0, W1, b1, (unsigned short*)h1, acc1);
  l2_fused<<<512, 256, 0, stream>>>(h1, acc1, g1, be1, W2, b2, maxb, minb, acc2);
  final_kernel<<<4096, 256, 0, stream>>>(xyz, maxb, minb, acc2, g2, be2, out);
}